// Round 1
// baseline (2385.201 us; speedup 1.0000x reference)
//
#include <hip/hip_runtime.h>

#define E_N 160000
#define N_N 10000
#define HD  128
#define LAY 16

constexpr int WSTRIDE = 136; // 128 + 8 pad shorts: 272B row stride, 16B aligned, uniform banks

typedef __attribute__((ext_vector_type(8))) short short8;
typedef __attribute__((ext_vector_type(4))) float f32x4;

__device__ __forceinline__ unsigned short f2bf(float f){
  union { float f; unsigned u; } v; v.f = f;
  unsigned r = v.u + 0x7FFFu + ((v.u >> 16) & 1u);   // RNE
  return (unsigned short)(r >> 16);
}

__device__ __forceinline__ short8 ld8(const unsigned short* p){
  return *reinterpret_cast<const short8*>(p);
}

// stage a [128 n][128 k] bf16 tile (row-major [n][Kfull], offset kofs) into LDS
__device__ __forceinline__ void stage_w(unsigned short* lds, const unsigned short* __restrict__ g,
                                        int Kfull, int kofs, int tid){
  #pragma unroll
  for (int i = 0; i < 8; ++i){
    int cid = i*256 + tid;
    int n = cid >> 4, kc = cid & 15;
    uint4 v = *reinterpret_cast<const uint4*>(g + (size_t)n*Kfull + kofs + kc*8);
    *reinterpret_cast<uint4*>(lds + n*WSTRIDE + kc*8) = v;
  }
}

// ---------------- edge kernel: 128 edges/block, 4 waves x (32 rows x 128 cols) ----------------
__global__ __launch_bounds__(256, 2)
void edge_kernel(float* __restrict__ ef, unsigned short* __restrict__ ef_bf,
                 const unsigned short* __restrict__ nf_bf,
                 const int* __restrict__ src, const int* __restrict__ dst,
                 const unsigned short* __restrict__ wt1, const unsigned short* __restrict__ wt2,
                 const float* __restrict__ b1, const float* __restrict__ b2,
                 const float* __restrict__ g, const float* __restrict__ bt,
                 float* __restrict__ agg)
{
  __shared__ unsigned short Wbuf[128*WSTRIDE];
  __shared__ unsigned short Htile[128*WSTRIDE];
  const int tid = threadIdx.x, w = tid >> 6, lane = tid & 63, quad = lane >> 4, l16 = lane & 15;
  const int rbase = w*32;
  const long e0 = (long)blockIdx.x * 128;

  // per-lane A row pointers for the 3 concat segments (ef | nf[src] | nf[dst])
  const unsigned short* pA[2][3];
  #pragma unroll
  for (int a=0;a<2;a++){
    long e = e0 + rbase + a*16 + l16;
    pA[a][0] = ef_bf + e*HD;
    pA[a][1] = nf_bf + (long)src[e]*HD;
    pA[a][2] = nf_bf + (long)dst[e]*HD;
  }

  f32x4 acc[16];
  #pragma unroll
  for (int i=0;i<16;i++) acc[i] = (f32x4){0.f,0.f,0.f,0.f};

  // GEMM1: [128,384] @ [384,128], K chunks of 128 == concat segments
  #pragma unroll
  for (int c=0;c<3;c++){
    stage_w(Wbuf, wt1, 384, c*128, tid);
    __syncthreads();
    #pragma unroll
    for (int kk=0;kk<4;kk++){
      const int klocal = kk*32 + quad*8;
      short8 afr0 = ld8(pA[0][c] + klocal);
      short8 afr1 = ld8(pA[1][c] + klocal);
      #pragma unroll
      for (int j=0;j<8;j++){
        short8 bfr = ld8(&Wbuf[(j*16+l16)*WSTRIDE + klocal]);
        acc[j]   = __builtin_amdgcn_mfma_f32_16x16x32_bf16(afr0, bfr, acc[j],   0,0,0);
        acc[8+j] = __builtin_amdgcn_mfma_f32_16x16x32_bf16(afr1, bfr, acc[8+j], 0,0,0);
      }
    }
    __syncthreads();
  }

  // bias + SiLU -> Htile (bf16, A-operand friendly row-major layout)
  float b1v[8];
  #pragma unroll
  for (int j=0;j<8;j++) b1v[j] = b1[j*16+l16];
  #pragma unroll
  for (int a=0;a<2;a++){
    #pragma unroll
    for (int j=0;j<8;j++){
      #pragma unroll
      for (int r=0;r<4;r++){
        float y = acc[a*8+j][r] + b1v[j];
        float h = y / (1.f + __expf(-y));
        Htile[(rbase + a*16 + quad*4 + r)*WSTRIDE + j*16 + l16] = f2bf(h);
      }
    }
  }
  stage_w(Wbuf, wt2, 128, 0, tid);
  __syncthreads();

  // GEMM2: [128,128] @ [128,128]
  #pragma unroll
  for (int i=0;i<16;i++) acc[i] = (f32x4){0.f,0.f,0.f,0.f};
  #pragma unroll
  for (int kk=0;kk<4;kk++){
    const int klocal = kk*32 + quad*8;
    short8 afr0 = ld8(&Htile[(rbase +      l16)*WSTRIDE + klocal]);
    short8 afr1 = ld8(&Htile[(rbase + 16 + l16)*WSTRIDE + klocal]);
    #pragma unroll
    for (int j=0;j<8;j++){
      short8 bfr = ld8(&Wbuf[(j*16+l16)*WSTRIDE + klocal]);
      acc[j]   = __builtin_amdgcn_mfma_f32_16x16x32_bf16(afr0, bfr, acc[j],   0,0,0);
      acc[8+j] = __builtin_amdgcn_mfma_f32_16x16x32_bf16(afr1, bfr, acc[8+j], 0,0,0);
    }
  }

  // epilogue: +b2, LayerNorm, *g+b, residual (fp32), bf16 shadow, atomic scatter to agg
  float b2v[8], gv[8], btv[8];
  #pragma unroll
  for (int j=0;j<8;j++){ int col=j*16+l16; b2v[j]=b2[col]; gv[j]=g[col]; btv[j]=bt[col]; }
  #pragma unroll
  for (int a=0;a<2;a++){
    float s1[4]={0,0,0,0}, s2[4]={0,0,0,0};
    #pragma unroll
    for (int j=0;j<8;j++){
      #pragma unroll
      for (int r=0;r<4;r++){
        float y = acc[a*8+j][r] + b2v[j];
        acc[a*8+j][r] = y;
        s1[r]+=y; s2[r]+=y*y;
      }
    }
    #pragma unroll
    for (int m=1;m<16;m<<=1){
      #pragma unroll
      for (int r=0;r<4;r++){ s1[r]+=__shfl_xor(s1[r],m,64); s2[r]+=__shfl_xor(s2[r],m,64); }
    }
    #pragma unroll
    for (int r=0;r<4;r++){
      float mu  = s1[r]*(1.f/HD);
      float var = s2[r]*(1.f/HD) - mu*mu;
      float rstd = rsqrtf(var + 1e-5f);
      long e = e0 + rbase + a*16 + quad*4 + r;
      int dn = dst[e];
      float* efrow = ef + e*HD;
      unsigned short* efbrow = ef_bf + e*HD;
      float* aggrow = agg + (long)dn*HD;
      #pragma unroll
      for (int j=0;j<8;j++){
        int col = j*16+l16;
        float o  = (acc[a*8+j][r]-mu)*rstd*gv[j] + btv[j];
        float nv = efrow[col] + o;
        efrow[col]  = nv;
        efbrow[col] = f2bf(nv);
        atomicAdd(aggrow + col, nv);
      }
    }
  }
}

// ---------------- node kernel: 64 nodes/block, 4 waves x (16 rows x 128 cols) ----------------
__global__ __launch_bounds__(256, 2)
void node_kernel(float* __restrict__ nf, unsigned short* __restrict__ nf_bf,
                 const float* __restrict__ agg,
                 const unsigned short* __restrict__ wt1, const unsigned short* __restrict__ wt2,
                 const float* __restrict__ b1, const float* __restrict__ b2,
                 const float* __restrict__ g, const float* __restrict__ bt)
{
  __shared__ unsigned short Wbuf[128*WSTRIDE];
  __shared__ unsigned short Htile[64*WSTRIDE];
  const int tid = threadIdx.x, w = tid >> 6, lane = tid & 63, quad = lane >> 4, l16 = lane & 15;
  const int rbase = w*16;
  const long n0 = (long)blockIdx.x*64;
  long nl = n0 + rbase + l16; if (nl > N_N-1) nl = N_N-1;  // clamp for loads
  const float* pagg = agg + nl*HD;
  const unsigned short* pnf = nf_bf + nl*HD;

  f32x4 acc[8];
  #pragma unroll
  for (int i=0;i<8;i++) acc[i] = (f32x4){0.f,0.f,0.f,0.f};

  // GEMM1: [64,256] @ [256,128], chunk0 = agg (fp32, cvt in-frag), chunk1 = nf (bf16 shadow)
  #pragma unroll
  for (int c=0;c<2;c++){
    stage_w(Wbuf, wt1, 256, c*128, tid);
    __syncthreads();
    #pragma unroll
    for (int kk=0;kk<4;kk++){
      const int klocal = kk*32 + quad*8;
      short8 afr;
      if (c == 0){
        f32x4 u0 = *reinterpret_cast<const f32x4*>(pagg + klocal);
        f32x4 u1 = *reinterpret_cast<const f32x4*>(pagg + klocal + 4);
        #pragma unroll
        for (int i=0;i<4;i++){ afr[i] = (short)f2bf(u0[i]); afr[4+i] = (short)f2bf(u1[i]); }
      } else {
        afr = ld8(pnf + klocal);
      }
      #pragma unroll
      for (int j=0;j<8;j++){
        short8 bfr = ld8(&Wbuf[(j*16+l16)*WSTRIDE + klocal]);
        acc[j] = __builtin_amdgcn_mfma_f32_16x16x32_bf16(afr, bfr, acc[j], 0,0,0);
      }
    }
    __syncthreads();
  }

  float b1v[8];
  #pragma unroll
  for (int j=0;j<8;j++) b1v[j] = b1[j*16+l16];
  #pragma unroll
  for (int j=0;j<8;j++){
    #pragma unroll
    for (int r=0;r<4;r++){
      float y = acc[j][r] + b1v[j];
      float h = y / (1.f + __expf(-y));
      Htile[(rbase + quad*4 + r)*WSTRIDE + j*16 + l16] = f2bf(h);
    }
  }
  stage_w(Wbuf, wt2, 128, 0, tid);
  __syncthreads();

  #pragma unroll
  for (int i=0;i<8;i++) acc[i] = (f32x4){0.f,0.f,0.f,0.f};
  #pragma unroll
  for (int kk=0;kk<4;kk++){
    const int klocal = kk*32 + quad*8;
    short8 afr = ld8(&Htile[(rbase + l16)*WSTRIDE + klocal]);
    #pragma unroll
    for (int j=0;j<8;j++){
      short8 bfr = ld8(&Wbuf[(j*16+l16)*WSTRIDE + klocal]);
      acc[j] = __builtin_amdgcn_mfma_f32_16x16x32_bf16(afr, bfr, acc[j], 0,0,0);
    }
  }

  float b2v[8], gv[8], btv[8];
  #pragma unroll
  for (int j=0;j<8;j++){ int col=j*16+l16; b2v[j]=b2[col]; gv[j]=g[col]; btv[j]=bt[col]; }
  float s1[4]={0,0,0,0}, s2[4]={0,0,0,0};
  #pragma unroll
  for (int j=0;j<8;j++){
    #pragma unroll
    for (int r=0;r<4;r++){
      float y = acc[j][r] + b2v[j];
      acc[j][r] = y; s1[r]+=y; s2[r]+=y*y;
    }
  }
  #pragma unroll
  for (int m=1;m<16;m<<=1){
    #pragma unroll
    for (int r=0;r<4;r++){ s1[r]+=__shfl_xor(s1[r],m,64); s2[r]+=__shfl_xor(s2[r],m,64); }
  }
  #pragma unroll
  for (int r=0;r<4;r++){
    float mu  = s1[r]*(1.f/HD);
    float var = s2[r]*(1.f/HD) - mu*mu;
    float rstd = rsqrtf(var + 1e-5f);
    long nr = n0 + rbase + quad*4 + r;
    if (nr < N_N){
      float* nrow = nf + nr*HD;
      unsigned short* nbrow = nf_bf + nr*HD;
      #pragma unroll
      for (int j=0;j<8;j++){
        int col = j*16+l16;
        float o  = (acc[j][r]-mu)*rstd*gv[j] + btv[j];
        float nv = nrow[col] + o;
        nrow[col]  = nv;
        nbrow[col] = f2bf(nv);
      }
    }
  }
}

// ---------------- utility kernels ----------------
__global__ void zero_f32(float* __restrict__ p, long n){
  long i = ((long)blockIdx.x*256 + threadIdx.x)*4;
  if (i < n) *reinterpret_cast<f32x4*>(p+i) = (f32x4){0.f,0.f,0.f,0.f};
}

__global__ void cvt_bf16(const float* __restrict__ s, unsigned short* __restrict__ d, long n){
  long i = ((long)blockIdx.x*256 + threadIdx.x)*8;
  if (i >= n) return;
  f32x4 a = *reinterpret_cast<const f32x4*>(s+i);
  f32x4 b = *reinterpret_cast<const f32x4*>(s+i+4);
  short8 v;
  #pragma unroll
  for (int k=0;k<4;k++){ v[k] = (short)f2bf(a[k]); v[4+k] = (short)f2bf(b[k]); }
  *reinterpret_cast<short8*>(d+i) = v;
}

// s: [L][K][128] fp32 -> d: [L][128][K] bf16 (transposed so B-frags read k-contiguous)
__global__ void transpose_w(const float* __restrict__ s, unsigned short* __restrict__ d, int K, long total){
  long idx = (long)blockIdx.x*256 + threadIdx.x;
  if (idx >= total) return;
  int k = (int)(idx % K);
  long t = idx / K;
  int n = (int)(t % 128);
  long l = t / 128;
  d[idx] = f2bf(s[(l*K + k)*128 + n]);
}

extern "C" void kernel_launch(void* const* d_in, const int* in_sizes, int n_in,
                              void* d_out, int out_size, void* d_ws, size_t ws_size,
                              hipStream_t stream) {
  const float* efeat = (const float*)d_in[0];
  const float* nfeat = (const float*)d_in[1];
  const int*   src   = (const int*)d_in[2];
  const int*   dst   = (const int*)d_in[3];
  const float* eW1 = (const float*)d_in[4];
  const float* eb1 = (const float*)d_in[5];
  const float* eW2 = (const float*)d_in[6];
  const float* eb2 = (const float*)d_in[7];
  const float* eg  = (const float*)d_in[8];
  const float* ebt = (const float*)d_in[9];
  const float* nW1 = (const float*)d_in[10];
  const float* nb1 = (const float*)d_in[11];
  const float* nW2 = (const float*)d_in[12];
  const float* nb2 = (const float*)d_in[13];
  const float* ng  = (const float*)d_in[14];
  const float* nbt = (const float*)d_in[15];

  float* ef = (float*)d_out;                  // residual stream lives in d_out
  float* nf = (float*)d_out + (long)E_N*HD;

  char* ws = (char*)d_ws;
  float* agg = (float*)ws;                    ws += (long)N_N*HD*4;
  unsigned short* ef_bf = (unsigned short*)ws; ws += (long)E_N*HD*2;
  unsigned short* nf_bf = (unsigned short*)ws; ws += (long)N_N*HD*2;
  unsigned short* wt1e = (unsigned short*)ws;  ws += (long)LAY*128*384*2;
  unsigned short* wt2e = (unsigned short*)ws;  ws += (long)LAY*128*128*2;
  unsigned short* wt1n = (unsigned short*)ws;  ws += (long)LAY*128*256*2;
  unsigned short* wt2n = (unsigned short*)ws;

  hipMemcpyAsync(ef, efeat, (long)E_N*HD*4, hipMemcpyDeviceToDevice, stream);
  hipMemcpyAsync(nf, nfeat, (long)N_N*HD*4, hipMemcpyDeviceToDevice, stream);
  cvt_bf16<<<(E_N*HD/8 + 255)/256, 256, 0, stream>>>(efeat, ef_bf, (long)E_N*HD);
  cvt_bf16<<<(N_N*HD/8 + 255)/256, 256, 0, stream>>>(nfeat, nf_bf, (long)N_N*HD);

  long t1e = (long)LAY*128*384, t2e = (long)LAY*128*128;
  long t1n = (long)LAY*128*256, t2n = (long)LAY*128*128;
  transpose_w<<<(t1e+255)/256, 256, 0, stream>>>(eW1, wt1e, 384, t1e);
  transpose_w<<<(t2e+255)/256, 256, 0, stream>>>(eW2, wt2e, 128, t2e);
  transpose_w<<<(t1n+255)/256, 256, 0, stream>>>(nW1, wt1n, 256, t1n);
  transpose_w<<<(t2n+255)/256, 256, 0, stream>>>(nW2, wt2n, 128, t2n);

  for (int l = 0; l < LAY; ++l){
    zero_f32<<<1250, 256, 0, stream>>>(agg, (long)N_N*HD);
    edge_kernel<<<E_N/128, 256, 0, stream>>>(ef, ef_bf, nf_bf, src, dst,
        wt1e + (long)l*128*384, wt2e + (long)l*128*128,
        eb1 + l*HD, eb2 + l*HD, eg + l*HD, ebt + l*HD, agg);
    node_kernel<<<(N_N + 63)/64, 256, 0, stream>>>(nf, nf_bf, agg,
        wt1n + (long)l*128*256, wt2n + (long)l*128*128,
        nb1 + l*HD, nb2 + l*HD, ng + l*HD, nbt + l*HD);
  }
}